// Round 5
// baseline (90.633 us; speedup 1.0000x reference)
//
#include <hip/hip_runtime.h>
#include <math.h>

// RecurrentNALU single step, fp32. B=4096, IN=128, HID=128, CAT=256.
// R5: 2-D lane tiling. Wave = 8 rows x 8 cols (r=lane>>3, j=lane&7), each lane
// owns a 2x2 output micro-tile (rows r,r+8; cols j,j+8). Weights: per-lane
// global b128 loads, 8 lanes/address -> full-rate coalescing, L1-resident.
// x: staged once into 32 KB c-major LDS with XOR bank swizzle, conflict-free
// group reads, no barriers in the main loop. Block = 4 waves = 32r x 32c tile.

#define BATCH  4096
#define HID    128
#define CAT    256
#define ROWS_B 32
#define COLS_B 32
#define GRID   ((BATCH / ROWS_B) * (HID / COLS_B))  // 128*4 = 512

typedef float f32x2 __attribute__((ext_vector_type(2)));
typedef float f32x4 __attribute__((ext_vector_type(4)));

static __device__ __forceinline__ f32x2 pk_fma(f32x2 a, f32x2 b, f32x2 c) {
#if __has_builtin(__builtin_elementwise_fma)
    return __builtin_elementwise_fma(a, b, c);
#else
    f32x2 r; r.x = fmaf(a.x, b.x, c.x); r.y = fmaf(a.y, b.y, c.y); return r;
#endif
}
static __device__ __forceinline__ f32x4 clamp4(f32x4 v, float lo, float hi) {
#if __has_builtin(__builtin_elementwise_min) && __has_builtin(__builtin_elementwise_max)
    return __builtin_elementwise_min(
               __builtin_elementwise_max(v, (f32x4){lo, lo, lo, lo}),
               (f32x4){hi, hi, hi, hi});
#else
    f32x4 r;
    r.x = fminf(fmaxf(v.x, lo), hi); r.y = fminf(fmaxf(v.y, lo), hi);
    r.z = fminf(fmaxf(v.z, lo), hi); r.w = fminf(fmaxf(v.w, lo), hi);
    return r;
#endif
}

__global__ __launch_bounds__(256, 2)
void nalu_step_kernel(const float* __restrict__ x_t,
                      const float* __restrict__ h_tm1,
                      const float* __restrict__ Wa_,
                      const float* __restrict__ Wm_,
                      const float* __restrict__ Ga_,
                      float* __restrict__ out)
{
    // c-major swizzled: float idx = cq*128 + ((rr&24) | ((rr^cq)&7))*4 + k
    __shared__ float xs[ROWS_B * CAT]; // 32 KB

    // XCD-bijective swizzle (512 % 8 == 0)
    const int bid = blockIdx.x;
    const int wg  = (bid & 7) * (GRID >> 3) + (bid >> 3);
    const int rowBase = (wg >> 2) * ROWS_B;   // 128 row tiles
    const int colBase = (wg & 3) * COLS_B;    // 4 col tiles

    const int tid = threadIdx.x;

    // ---- stage x = concat(x_t, h_tm1): 32 rows x 64 quads ----
    // thread t -> quad uq = t&7 (+8 per iter), row rr = t>>3. Global reads:
    // 8 lanes consecutive quads within a row -> 8 full 128B lines per instr.
    {
        const int uq = tid & 7;
        const int rr = tid >> 3;
        const float* __restrict__ rowx = x_t   + (size_t)(rowBase + rr) * 128;
        const float* __restrict__ rowh = h_tm1 + (size_t)(rowBase + rr) * 128;
        #pragma unroll
        for (int k = 0; k < 8; ++k) {
            const int cq = uq + 8 * k;
            const f32x4 v = (k < 4)
                ? *reinterpret_cast<const f32x4*>(rowx + cq * 4)
                : *reinterpret_cast<const f32x4*>(rowh + cq * 4 - 128);
            const int slot = (rr & 24) | ((rr ^ cq) & 7);
            *reinterpret_cast<f32x4*>(&xs[cq * 128 + slot * 4]) = v;
        }
    }
    __syncthreads();

    const int lane = tid & 63;
    const int wid  = __builtin_amdgcn_readfirstlane(tid >> 6); // 0..3
    const int r    = lane >> 3;                 // 0..7 (row within half-tile)
    const int j    = lane & 7;                  // 0..7 (col within half-tile)
    const int rowHalf = (wid >> 1) * 16;        // 0 or 16
    const int colHalf = (wid & 1) * 16;         // 0 or 16

    const int h0 = colBase + colHalf + j;       // first owned col
    const int h1 = h0 + 8;                      // second owned col

    const float* __restrict__ pA0 = Wa_ + (size_t)h0 * CAT;
    const float* __restrict__ pA1 = Wa_ + (size_t)h1 * CAT;
    const float* __restrict__ pM0 = Wm_ + (size_t)h0 * CAT;
    const float* __restrict__ pM1 = Wm_ + (size_t)h1 * CAT;
    const float* __restrict__ pG0 = Ga_ + (size_t)h0 * CAT;
    const float* __restrict__ pG1 = Ga_ + (size_t)h1 * CAT;

    // accumulators: [row-idx][col-idx], f32x2 packed over c-pairs
    f32x2 aa00 = {0,0}, aa01 = {0,0}, aa10 = {0,0}, aa11 = {0,0};
    f32x2 ag00 = {0,0}, ag01 = {0,0}, ag10 = {0,0}, ag11 = {0,0};
    f32x2 am00 = {1,1}, am01 = {1,1}, am10 = {1,1}, am11 = {1,1};

    const f32x2 one2 = {1.f, 1.f};

    #pragma unroll 4
    for (int cq = 0; cq < CAT / 4; ++cq) {
        // x: two conflict-free group reads (rows r and r+8 of this half-tile)
        const int s0 = cq * 128 + (rowHalf + ((r ^ cq) & 7)) * 4;
        const f32x4 xv0 = *reinterpret_cast<const f32x4*>(&xs[s0]);
        const f32x4 xv1 = *reinterpret_cast<const f32x4*>(&xs[s0 + 32]);
        const f32x2 xl0 = {xv0.x, xv0.y}, xh0 = {xv0.z, xv0.w};
        const f32x2 xl1 = {xv1.x, xv1.y}, xh1 = {xv1.z, xv1.w};

        // weights: per-lane b128 loads, 8 lanes/address, imm offsets
        const f32x4 wa0 = clamp4(*reinterpret_cast<const f32x4*>(pA0 + cq * 4), -1.f, 1.f);
        const f32x4 wa1 = clamp4(*reinterpret_cast<const f32x4*>(pA1 + cq * 4), -1.f, 1.f);
        const f32x4 wm0 = clamp4(*reinterpret_cast<const f32x4*>(pM0 + cq * 4),  0.f, 1.f);
        const f32x4 wm1 = clamp4(*reinterpret_cast<const f32x4*>(pM1 + cq * 4),  0.f, 1.f);
        const f32x4 ga0 = *reinterpret_cast<const f32x4*>(pG0 + cq * 4);
        const f32x4 ga1 = *reinterpret_cast<const f32x4*>(pG1 + cq * 4);

        const f32x2 wal0 = {wa0.x, wa0.y}, wah0 = {wa0.z, wa0.w};
        const f32x2 wal1 = {wa1.x, wa1.y}, wah1 = {wa1.z, wa1.w};
        const f32x2 wml0 = {wm0.x, wm0.y}, wmh0 = {wm0.z, wm0.w};
        const f32x2 wml1 = {wm1.x, wm1.y}, wmh1 = {wm1.z, wm1.w};
        const f32x2 gal0 = {ga0.x, ga0.y}, gah0 = {ga0.z, ga0.w};
        const f32x2 gal1 = {ga1.x, ga1.y}, gah1 = {ga1.z, ga1.w};
        // m-term: x*wm + 1 - wm == fma(wm, x, 1-wm); precompute (1-wm) per col
        const f32x2 ql0 = one2 - wml0, qh0 = one2 - wmh0;
        const f32x2 ql1 = one2 - wml1, qh1 = one2 - wmh1;

        // row 0 (r), col 0 (h0)
        aa00 = pk_fma(xl0, wal0, aa00); aa00 = pk_fma(xh0, wah0, aa00);
        ag00 = pk_fma(xl0, gal0, ag00); ag00 = pk_fma(xh0, gah0, ag00);
        am00 = am00 * pk_fma(wml0, xl0, ql0);
        am00 = am00 * pk_fma(wmh0, xh0, qh0);
        // row 0, col 1 (h1)
        aa01 = pk_fma(xl0, wal1, aa01); aa01 = pk_fma(xh0, wah1, aa01);
        ag01 = pk_fma(xl0, gal1, ag01); ag01 = pk_fma(xh0, gah1, ag01);
        am01 = am01 * pk_fma(wml1, xl0, ql1);
        am01 = am01 * pk_fma(wmh1, xh0, qh1);
        // row 1 (r+8), col 0
        aa10 = pk_fma(xl1, wal0, aa10); aa10 = pk_fma(xh1, wah0, aa10);
        ag10 = pk_fma(xl1, gal0, ag10); ag10 = pk_fma(xh1, gah0, ag10);
        am10 = am10 * pk_fma(wml0, xl1, ql0);
        am10 = am10 * pk_fma(wmh0, xh1, qh0);
        // row 1, col 1
        aa11 = pk_fma(xl1, wal1, aa11); aa11 = pk_fma(xh1, wah1, aa11);
        ag11 = pk_fma(xl1, gal1, ag11); ag11 = pk_fma(xh1, gah1, ag11);
        am11 = am11 * pk_fma(wml1, xl1, ql1);
        am11 = am11 * pk_fma(wmh1, xh1, qh1);
    }

    // ---- epilogue: sigmoid gate + blend; stores coalesced over j ----
    const int row0 = rowBase + rowHalf + r;
#define FINISH(AA, AG, AM, ROWOFF, HCOL)                                       \
    do {                                                                       \
        const float a = (AA).x + (AA).y;                                       \
        const float z = (AG).x + (AG).y;                                       \
        const float m = (AM).x * (AM).y;                                       \
        const float g = 1.0f / (1.0f + __expf(-z));                            \
        out[(size_t)(row0 + (ROWOFF)) * HID + (HCOL)] = g * a + (1.0f - g) * m;\
    } while (0)

    FINISH(aa00, ag00, am00, 0, h0);
    FINISH(aa01, ag01, am01, 0, h1);
    FINISH(aa10, ag10, am10, 8, h0);
    FINISH(aa11, ag11, am11, 8, h1);
#undef FINISH
}

extern "C" void kernel_launch(void* const* d_in, const int* in_sizes, int n_in,
                              void* d_out, int out_size, void* d_ws, size_t ws_size,
                              hipStream_t stream)
{
    const float* x_t   = (const float*)d_in[0];
    const float* h_tm1 = (const float*)d_in[1];
    const float* W_add = (const float*)d_in[2];
    const float* W_mul = (const float*)d_in[3];
    const float* G_add = (const float*)d_in[4];
    float* out = (float*)d_out;

    nalu_step_kernel<<<GRID, 256, 0, stream>>>(x_t, h_tm1, W_add, W_mul, G_add, out);
}

// Round 6
// 24.951 us; speedup vs baseline: 3.6324x; 3.6324x over previous
//
#include <hip/hip_runtime.h>
#include <math.h>

// RecurrentNALU single step, fp32. B=4096, IN=128, HID=128, CAT=256.
// R6: weights staged (pre-clamped, interleaved) into LDS and read as
// uniform-address ds_read_b128 broadcasts -> no per-lane VMEM in the main
// loop (R4/R5 showed divergent wave-loads cost ~70cyc/instr), no SMEM in the
// main loop (R1 showed s_load pollutes the in-order lgkm domain with LDS).
// lane = row; wave = 64 rows x 4 cols; block = 4 waves = 64r x 16c.
// x double-buffered quad-major in LDS with slot = r ^ (cq&3) bank swizzle.

#define BATCH   4096
#define HID     128
#define CAT     256
#define ROWS_B  64
#define COLS_B  16
#define CPW     4              // cols per wave
#define CHUNK   64             // c per x chunk
#define NCHUNK  4
#define CQC     16             // c-quads per chunk
#define GRID    ((BATCH / ROWS_B) * (HID / COLS_B)) // 64*8 = 512

typedef float f32x2 __attribute__((ext_vector_type(2)));
typedef float f32x4 __attribute__((ext_vector_type(4)));

static __device__ __forceinline__ f32x2 pk_fma(f32x2 a, f32x2 b, f32x2 c) {
#if __has_builtin(__builtin_elementwise_fma)
    return __builtin_elementwise_fma(a, b, c);
#else
    f32x2 r; r.x = fmaf(a.x, b.x, c.x); r.y = fmaf(a.y, b.y, c.y); return r;
#endif
}
static __device__ __forceinline__ f32x4 clamp4(f32x4 v, float lo, float hi) {
#if __has_builtin(__builtin_elementwise_min) && __has_builtin(__builtin_elementwise_max)
    return __builtin_elementwise_min(
               __builtin_elementwise_max(v, (f32x4){lo, lo, lo, lo}),
               (f32x4){hi, hi, hi, hi});
#else
    f32x4 r;
    r.x = fminf(fmaxf(v.x, lo), hi); r.y = fminf(fmaxf(v.y, lo), hi);
    r.z = fminf(fmaxf(v.z, lo), hi); r.w = fminf(fmaxf(v.w, lo), hi);
    return r;
#endif
}

__global__ __launch_bounds__(256, 2)
void nalu_step_kernel(const float* __restrict__ x_t,
                      const float* __restrict__ h_tm1,
                      const float* __restrict__ Wa_,
                      const float* __restrict__ Wm_,
                      const float* __restrict__ Ga_,
                      float* __restrict__ out)
{
    // weights: [col][cq][12] = (wa0..3, ga0..3, wm0..3), pre-clamped. 48 KB.
    __shared__ float wl[COLS_B * 64 * 12];
    // x: [buf][cq_local][slot][4], slot = r ^ (cq_local & 3). 2 x 16 KB.
    __shared__ float xs[2][CQC][64][4];

    // XCD-bijective block swizzle (512 % 8 == 0)
    const int bid = blockIdx.x;
    const int wg  = (bid & 7) * (GRID >> 3) + (bid >> 3);
    const int rowBase = (wg >> 3) * ROWS_B;  // 64 row-blocks
    const int colBase = (wg & 7) * COLS_B;   // 8 col-blocks

    const int tid = threadIdx.x;

    // ---- stage weights once: coalesced global reads, pre-clamp, interleave ----
    #pragma unroll
    for (int it = 0; it < 4; ++it) {
        const int q   = tid + it * 256;   // 0..1023 = 16 cols x 64 cq
        const int col = q >> 6;
        const int cq  = q & 63;
        const size_t goff = (size_t)(colBase + col) * CAT + cq * 4;
        const f32x4 wa = clamp4(*reinterpret_cast<const f32x4*>(Wa_ + goff), -1.f, 1.f);
        const f32x4 ga = *reinterpret_cast<const f32x4*>(Ga_ + goff);
        const f32x4 wm = clamp4(*reinterpret_cast<const f32x4*>(Wm_ + goff),  0.f, 1.f);
        float* d = &wl[(col * 64 + cq) * 12];
        *reinterpret_cast<f32x4*>(d + 0) = wa;
        *reinterpret_cast<f32x4*>(d + 4) = ga;
        *reinterpret_cast<f32x4*>(d + 8) = wm;
    }

    // ---- x chunk staging: thread t -> row r = t>>2, k = t&3 ----
#define STAGE(CH, BUF)                                                         \
    do {                                                                       \
        const int r_ = tid >> 2;                                               \
        const int k_ = tid & 3;                                                \
        const float* __restrict__ srow = ((CH) < 2)                            \
            ? (x_t   + (size_t)(rowBase + r_) * 128 + (CH) * 64)               \
            : (h_tm1 + (size_t)(rowBase + r_) * 128 + ((CH) - 2) * 64);        \
        _Pragma("unroll")                                                      \
        for (int it = 0; it < 4; ++it) {                                       \
            const int cql = k_ + it * 4;                                       \
            const f32x4 v = *reinterpret_cast<const f32x4*>(srow + cql * 4);   \
            *reinterpret_cast<f32x4*>(&xs[BUF][cql][r_ ^ k_][0]) = v;          \
        }                                                                      \
    } while (0)

    STAGE(0, 0);
    __syncthreads();

    const int lane = tid & 63;
    const int wid  = __builtin_amdgcn_readfirstlane(tid >> 6); // 0..3

    // per-col LDS base pointers (loop-invariant; cq indexes via imm offsets)
    const float* __restrict__ w0 = &wl[(wid * CPW + 0) * 768];
    const float* __restrict__ w1 = &wl[(wid * CPW + 1) * 768];
    const float* __restrict__ w2 = &wl[(wid * CPW + 2) * 768];
    const float* __restrict__ w3 = &wl[(wid * CPW + 3) * 768];

    f32x2 aa[CPW], ag[CPW], am[CPW];
    #pragma unroll
    for (int j = 0; j < CPW; ++j) {
        aa[j] = (f32x2){0.f, 0.f};
        ag[j] = (f32x2){0.f, 0.f};
        am[j] = (f32x2){1.f, 1.f};
    }
    const f32x2 one2 = {1.f, 1.f};

    #pragma unroll
    for (int ch = 0; ch < NCHUNK; ++ch) {
        const int cur = ch & 1;
        if (ch == 0) STAGE(1, 1);
        if (ch == 1) STAGE(2, 0);
        if (ch == 2) STAGE(3, 1);

        const int wchunk = ch * CQC * 12; // chunk offset into per-col weights

        #pragma unroll 4
        for (int cql = 0; cql < CQC; ++cql) {
            const f32x4 xv = *reinterpret_cast<const f32x4*>(
                &xs[cur][cql][lane ^ (cql & 3)][0]);
            const f32x2 xlo = {xv.x, xv.y}, xhi = {xv.z, xv.w};
            const f32x2 mlo = xlo - one2, mhi = xhi - one2;

            const float* wj[CPW] = {w0 + wchunk + cql * 12,
                                    w1 + wchunk + cql * 12,
                                    w2 + wchunk + cql * 12,
                                    w3 + wchunk + cql * 12};
            #pragma unroll
            for (int j = 0; j < CPW; ++j) {
                const f32x4 wa = *reinterpret_cast<const f32x4*>(wj[j] + 0);
                const f32x4 ga = *reinterpret_cast<const f32x4*>(wj[j] + 4);
                const f32x4 wm = *reinterpret_cast<const f32x4*>(wj[j] + 8);
                aa[j] = pk_fma(xlo, (f32x2){wa.x, wa.y}, aa[j]);
                aa[j] = pk_fma(xhi, (f32x2){wa.z, wa.w}, aa[j]);
                ag[j] = pk_fma(xlo, (f32x2){ga.x, ga.y}, ag[j]);
                ag[j] = pk_fma(xhi, (f32x2){ga.z, ga.w}, ag[j]);
                am[j] = am[j] * pk_fma((f32x2){wm.x, wm.y}, mlo, one2);
                am[j] = am[j] * pk_fma((f32x2){wm.z, wm.w}, mhi, one2);
            }
        }
        __syncthreads();
    }
#undef STAGE

    // ---- epilogue: sigmoid gate + blend ----
    const size_t orow = (size_t)(rowBase + lane) * HID + colBase + wid * CPW;
    #pragma unroll
    for (int j = 0; j < CPW; ++j) {
        const float a = aa[j].x + aa[j].y;
        const float z = ag[j].x + ag[j].y;
        const float m = am[j].x * am[j].y;
        const float g = 1.0f / (1.0f + __expf(-z));
        out[orow + j] = g * a + (1.0f - g) * m;
    }
}

extern "C" void kernel_launch(void* const* d_in, const int* in_sizes, int n_in,
                              void* d_out, int out_size, void* d_ws, size_t ws_size,
                              hipStream_t stream)
{
    const float* x_t   = (const float*)d_in[0];
    const float* h_tm1 = (const float*)d_in[1];
    const float* W_add = (const float*)d_in[2];
    const float* W_mul = (const float*)d_in[3];
    const float* G_add = (const float*)d_in[4];
    float* out = (float*)d_out;

    nalu_step_kernel<<<GRID, 256, 0, stream>>>(x_t, h_tm1, W_add, W_mul, G_add, out);
}